// Round 14
// baseline (173.467 us; speedup 1.0000x reference)
//
#include <hip/hip_runtime.h>

typedef unsigned short u16;
typedef unsigned int u32;
typedef __bf16 bf16x8 __attribute__((ext_vector_type(8)));
typedef float f32x4 __attribute__((ext_vector_type(4)));

#define AS1 __attribute__((address_space(1)))
#define AS3 __attribute__((address_space(3)))

// ---- fp32 <-> bf16 ----
__device__ inline u16 f2bf(float f) {
  union { float f; unsigned u; } a; a.f = f;
  unsigned u = a.u;
  return (u16)((u + 0x7fffu + ((u >> 16) & 1u)) >> 16);
}
__device__ inline float bf2f(u16 h) {
  union { unsigned u; float f; } a; a.u = ((u32)h) << 16; return a.f;
}

// ---- all fp32 -> bf16 converts in one dispatch ----
__global__ __launch_bounds__(256) void cvt_all_kernel(
    const float* __restrict__ x, const float* __restrict__ wq,
    const float* __restrict__ wk, const float* __restrict__ wv,
    u16* __restrict__ xb, u16* __restrict__ wqb,
    u16* __restrict__ wkb, u16* __restrict__ wvb) {
  int bid = blockIdx.x;
  const float* in; u16* out;
  if (bid < 8192) { in = x; out = xb; }
  else if (bid < 9216) { in = wq; out = wqb; bid -= 8192; }
  else if (bid < 10240) { in = wk; out = wkb; bid -= 9216; }
  else { in = wv; out = wvb; bid -= 10240; }
  size_t i = ((size_t)bid * 256 + threadIdx.x) * 4;
  float4 v = *(const float4*)(in + i);
  ushort4 o;
  o.x = f2bf(v.x); o.y = f2bf(v.y); o.z = f2bf(v.z); o.w = f2bf(v.w);
  *(ushort4*)(out + i) = o;
}

// ============================================================================
// 256x256 8-wave GEMM core, depth-2 prefetch + PIPELINED FRAG READS.
//   LDS 160KB: A ring-3 @ 0/16384/32768 (u16), B ping-pong @ 49152/65536.
//   NEW vs r12: A-fragment ds_reads are issued ONE PHASE AHEAD into a
//   statically-indexed ping-pong af[2] (region q reads phase q+1's frags;
//   q3 reads tile t+1's q0 frags). This takes the ~120-200cy LDS latency off
//   the per-phase critical path (was exposed at every barrier interval).
//   B-frags stay single-buffered (read at q0; exposed once/tile) for VGPRs.
//   vmcnt(6) at q2 (outstanding 14 = t+1's 8 + t+2's 6 -> completes t+1),
//   placed before q2's closing barrier which publishes tile t+1 for the
//   q3 read-ahead. Staging/dead-region schedule identical to r12 (proven).
// ============================================================================
template <typename CT>
__device__ __forceinline__ void gemm_core3(
    u16* __restrict__ lds,
    const u16* __restrict__ A, const u16* __restrict__ B, CT* __restrict__ C,
    int nt, int lda, int ldb, int ldc, int m0, int n0) {
  const int tid = threadIdx.x;
  const int ln = tid & 63, wv = tid >> 6;
  const int wr = wv >> 2, wc = wv & 3;

  auto sweep = [&](const u16* src, int ld, int t, int s, int base) {
    const int c = s * 512 + tid;
    const int row = c >> 3, slot = c & 7;
    const int col = (slot ^ (row & 7)) * 8;
    __builtin_amdgcn_global_load_lds(
        (const AS1 void*)(src + (size_t)row * ld + (size_t)t * 64 + col),
        (AS3 void*)(&lds[base + c * 8]), 16, 0, 0);
  };

  auto rdA = [&](const u16* La, int q, int mi, int ks) -> bf16x8 {
    const int row = wr * 128 + (q * 2 + mi) * 16 + (ln & 15);
    const int kc = ks * 4 + (ln >> 4);
    return *(const bf16x8*)&La[row * 64 + ((kc ^ (row & 7)) << 3)];
  };

  f32x4 acc[8][4] = {};
  bf16x8 af[2][2][2];   // [phase-parity][mi][ks] — all indices static post-unroll
  bf16x8 bfr[4][2];

  // prologue: tiles 0 and 1 fully staged; vmcnt(8) completes tile 0
#pragma unroll
  for (int s = 0; s < 4; ++s) sweep(B, ldb, 0, s, 49152);
#pragma unroll
  for (int s = 0; s < 4; ++s) sweep(A, lda, 0, s, 0);
  if (nt > 1) {
#pragma unroll
    for (int s = 0; s < 4; ++s) sweep(B, ldb, 1, s, 65536);
#pragma unroll
    for (int s = 0; s < 4; ++s) sweep(A, lda, 1, s, 16384);
    asm volatile("s_waitcnt vmcnt(8)" ::: "memory");
  } else {
    asm volatile("s_waitcnt vmcnt(0)" ::: "memory");
  }
  __builtin_amdgcn_s_barrier();

  // pre-read A-frags for (t=0, q0)
#pragma unroll
  for (int mi = 0; mi < 2; ++mi)
#pragma unroll
    for (int ks = 0; ks < 2; ++ks) af[0][mi][ks] = rdA(&lds[0], 0, mi, ks);

  for (int t = 0; t < nt; ++t) {
    const u16* La = &lds[(t % 3) * 16384];
    const u16* LaN = &lds[((t + 1) % 3) * 16384];
    const u16* Lb = &lds[49152 + (t & 1) * 16384];
    const int an = ((t + 2) % 3) * 16384;        // holds A(t-1): dead
    const int bn = 49152 + (t & 1) * 16384;      // self: dead after q0 reads
    const bool stg = (t + 2) < nt;
#pragma unroll
    for (int q = 0; q < 4; ++q) {
      __builtin_amdgcn_sched_barrier(0);         // pin reads below prev barrier
      if (q == 0) {
#pragma unroll
        for (int ni = 0; ni < 4; ++ni)
#pragma unroll
          for (int ks = 0; ks < 2; ++ks) {
            const int row = wc * 64 + ni * 16 + (ln & 15);
            const int kc = ks * 4 + (ln >> 4);
            bfr[ni][ks] = *(const bf16x8*)&Lb[row * 64 + ((kc ^ (row & 7)) << 3)];
          }
      }
      // read-ahead A-frags for the NEXT phase (static parity index)
      if (q < 3) {
#pragma unroll
        for (int mi = 0; mi < 2; ++mi)
#pragma unroll
          for (int ks = 0; ks < 2; ++ks)
            af[(q + 1) & 1][mi][ks] = rdA(La, q + 1, mi, ks);
      } else if (t + 1 < nt) {
#pragma unroll
        for (int mi = 0; mi < 2; ++mi)
#pragma unroll
          for (int ks = 0; ks < 2; ++ks)
            af[0][mi][ks] = rdA(LaN, 0, mi, ks);
      }
      // dead-region staging (unchanged from r12)
      if (stg) {
        if (q == 0)      { sweep(A, lda, t + 2, 0, an); sweep(A, lda, t + 2, 1, an); }
        else if (q == 1) { sweep(A, lda, t + 2, 2, an); sweep(A, lda, t + 2, 3, an); }
        else if (q == 2) { sweep(B, ldb, t + 2, 0, bn); sweep(B, ldb, t + 2, 1, bn); }
        else             { sweep(B, ldb, t + 2, 2, bn); sweep(B, ldb, t + 2, 3, bn); }
      }
      __builtin_amdgcn_s_barrier();
      __builtin_amdgcn_s_setprio(1);
#pragma unroll
      for (int mi = 0; mi < 2; ++mi)
#pragma unroll
        for (int ni = 0; ni < 4; ++ni)
#pragma unroll
          for (int ks = 0; ks < 2; ++ks)
            acc[q * 2 + mi][ni] = __builtin_amdgcn_mfma_f32_16x16x32_bf16(
                af[q & 1][mi][ks], bfr[ni][ks], acc[q * 2 + mi][ni], 0, 0, 0);
      __builtin_amdgcn_s_setprio(0);
      if (q == 2) {
        if (stg)             asm volatile("s_waitcnt vmcnt(6)" ::: "memory");
        else if (t + 1 < nt) asm volatile("s_waitcnt vmcnt(0)" ::: "memory");
      }
      __builtin_amdgcn_s_barrier();
    }
  }

  // epilogue: D col = lane&15 (n), row = (lane>>4)*4 + reg (m)
#pragma unroll
  for (int mi = 0; mi < 8; ++mi) {
    const int rbase = m0 + wr * 128 + mi * 16 + (ln >> 4) * 4;
#pragma unroll
    for (int ni = 0; ni < 4; ++ni) {
      const int col = n0 + wc * 64 + ni * 16 + (ln & 15);
#pragma unroll
      for (int r = 0; r < 4; ++r) {
        const float v = acc[mi][ni][r];
        CT* ptr = &C[(size_t)(rbase + r) * ldc + col];
        if constexpr (sizeof(CT) == 4) *(float*)ptr = v;
        else                           *ptr = f2bf(v);
      }
    }
  }
}

// ---- Q = x Wq^T, K = x Wk^T: 256 blocks of 256x256 (exactly 1 round) ----
__global__ __launch_bounds__(512, 2) void proj_qk_kernel(
    const u16* __restrict__ xb, const u16* __restrict__ wqb,
    const u16* __restrict__ wkb, u16* __restrict__ Qb, u16* __restrict__ Kb) {
  __shared__ __align__(16) u16 lds[81920];
  const int bid = blockIdx.x;
  const int w = bid >> 7, r = bid & 127;
  const int rb = r >> 2, n0 = (r & 3) * 256;
  const u16* B = w ? wkb : wqb;
  u16* C = w ? Kb : Qb;
  gemm_core3<u16>(lds, xb + (size_t)rb * 256 * 1024, B + (size_t)n0 * 1024,
                  C, 16, 1024, 1024, 1024, rb * 256, n0);
}

// ---- qktvt: 256 coarse blocks, XCD-locality swizzled (round-10 proven).
//   items 0..143: qkt (S bf16), items 144..255: vt coarse keys 0..1791 ----
__global__ __launch_bounds__(512, 2) void qktvt_kernel(
    const u16* __restrict__ Qb, const u16* __restrict__ Kb, u16* __restrict__ Sb16,
    const u16* __restrict__ wvb, const u16* __restrict__ xb, u16* __restrict__ VTb) {
  __shared__ __align__(16) u16 lds[81920];
  const int bid = blockIdx.x;
  const int item = (bid & 7) * 32 + (bid >> 3);   // bijective 0..255
  if (item < 144) {
    const int z = item / 36, xt = item % 36;
    int m = 0;
    while ((m + 1) * (m + 2) / 2 <= xt) ++m;
    const int n = xt - m * (m + 1) / 2;
    gemm_core3<u16>(lds,
        Qb + ((size_t)z * 2048 + m * 256) * 1024,
        Kb + ((size_t)z * 2048 + n * 256) * 1024,
        Sb16 + (size_t)z * 2048 * 2048,
        16, 1024, 1024, 2048, m * 256, n * 256);
  } else {
    const int j = item - 144;                 // 0..111
    const int z = j / 28, r2 = j % 28, d = r2 / 7, kb = r2 % 7;
    gemm_core3<u16>(lds, wvb + (size_t)d * 256 * 1024,
                    xb + (size_t)z * 2048 * 1024 + (size_t)kb * 256 * 1024,
                    VTb + (size_t)z * 1024 * 2048,
                    16, 1024, 1024, 2048, d * 256, kb * 256);
  }
}

// ---- smvt: 64 vtK chunks (nt=4, K-quarters) + 512 softmax blocks ----
__global__ __launch_bounds__(512, 2) void smvt_kernel(
    u16* __restrict__ Sb16, float* __restrict__ R,
    const u16* __restrict__ wvb, const u16* __restrict__ xb) {
  __shared__ __align__(16) u16 lds[81920];
  const int bid = blockIdx.x;
  const int tid = threadIdx.x;
  if (bid < 64) {
    const int z = bid >> 4, r = bid & 15;
    const int d = r >> 2, h = r & 3;
    const u16* A = wvb + (size_t)d * 256 * 1024 + h * 256;
    const u16* B = xb + ((size_t)z * 2048 + 1792) * 1024 + h * 256;
    float* C = R + (size_t)z * 2097152 + (d * 4 + h) * 65536;
    gemm_core3<float>(lds, A, B, C, 4, 1024, 1024, 256, 0, 0);
    return;
  }
  // softmax on bf16 S: 16 rows per block, desc-m
  const int j = bid - 64;
  const int m = 7 - (j >> 6), z = (j >> 4) & 3, s = j & 15;
  const int iters = (m + 2) >> 1;            // ceil((m+1)*256 / 512)
  const int wvid = tid >> 6, lane = tid & 63;
  u16* S0 = Sb16 + (size_t)z * 2048 * 2048;
  for (int rr = wvid; rr < 16; rr += 8) {
    const int r = m * 256 + s * 16 + rr;
    u16* row = S0 + (size_t)r * 2048;
    float vals[4][8];
    float mx = -3.4e38f;
#pragma unroll
    for (int it2 = 0; it2 < 4; ++it2)
      if (it2 < iters) {
        const int idx8 = it2 * 512 + lane * 8;
        uint4 w = *(const uint4*)(row + idx8);
        const u32 ws[4] = {w.x, w.y, w.z, w.w};
#pragma unroll
        for (int e = 0; e < 8; ++e) {
          const u16 hb = (u16)(ws[e >> 1] >> ((e & 1) * 16));
          const float xv = bf2f(hb) * 0.03125f;
          vals[it2][e] = (idx8 + e <= r) ? xv : -3.4e38f;
          mx = fmaxf(mx, vals[it2][e]);
        }
      }
#pragma unroll
    for (int o = 32; o; o >>= 1) mx = fmaxf(mx, __shfl_xor(mx, o, 64));
    float sum = 0.f;
#pragma unroll
    for (int it2 = 0; it2 < 4; ++it2)
      if (it2 < iters) {
#pragma unroll
        for (int e = 0; e < 8; ++e) {
          const float pp = __expf(vals[it2][e] - mx);
          vals[it2][e] = pp;
          sum += pp;
        }
      }
#pragma unroll
    for (int o = 32; o; o >>= 1) sum += __shfl_xor(sum, o, 64);
    const float rcp = 1.f / sum;
#pragma unroll
    for (int it2 = 0; it2 < 4; ++it2)
      if (it2 < iters) {
        const int idx8 = it2 * 512 + lane * 8;
        uint4 w;
        u32 wo[4];
#pragma unroll
        for (int e2 = 0; e2 < 4; ++e2) {
          const u16 lo = f2bf(vals[it2][e2 * 2] * rcp);
          const u16 hi = f2bf(vals[it2][e2 * 2 + 1] * rcp);
          wo[e2] = (u32)lo | ((u32)hi << 16);
        }
        w.x = wo[0]; w.y = wo[1]; w.z = wo[2]; w.w = wo[3];
        *(uint4*)(row + idx8) = w;
      }
  }
}

// ---- vtfix: VT[z][dims][keys 1792..2047] = bf16(sum of 4 K-quarter partials) ----
__global__ __launch_bounds__(256) void vtfix_kernel(const float* __restrict__ R,
                                                    u16* __restrict__ VTb) {
  const int bid = blockIdx.x;            // 32: z(4) x d(4) x rowhalf(2)
  const int z = bid >> 3, q = bid & 7;
  const int d = q >> 1, rh = q & 1;
  const float* P0 = R + (size_t)z * 2097152 + (d * 4 + 0) * 65536;
  const float* P1 = P0 + 65536;
  const float* P2 = P0 + 131072;
  const float* P3 = P0 + 196608;
  for (int k = threadIdx.x; k < 128 * 64; k += 256) {   // 128 dims x 64 float4
    const int dp = rh * 128 + (k >> 6), c4 = (k & 63) * 4;
    const size_t off = (size_t)dp * 256 + c4;
    float4 a = *(const float4*)(P0 + off);
    float4 b = *(const float4*)(P1 + off);
    float4 c = *(const float4*)(P2 + off);
    float4 e = *(const float4*)(P3 + off);
    ushort4 o;
    o.x = f2bf(a.x + b.x + c.x + e.x); o.y = f2bf(a.y + b.y + c.y + e.y);
    o.z = f2bf(a.z + b.z + c.z + e.z); o.w = f2bf(a.w + b.w + c.w + e.w);
    *(ushort4*)(VTb + (size_t)z * 1024 * 2048 + (size_t)(d * 256 + dp) * 2048 +
                1792 + c4) = o;
  }
}

// pv chunk classes (desc nt): m-tile, k0 (K-tiles), nt, slot (0=out,1=slot1,2=slot2)
__constant__ signed char CPM[16] = {5,5,7,7,7,6,4,4,6,6,3,3,1,2,2,0};
__constant__ signed char CPK[16] = {0,12,0,11,22,0,0,10,10,19,0,8,0,0,6,0};
__constant__ signed char CPN[16] = {12,12,11,11,10,10,10,10,9,9,8,8,8,6,6,4};
__constant__ signed char CPS[16] = {0,1,0,1,2,0,0,1,1,2,0,1,0,0,1,0};

// ---- O_b = P_b VT_b^T; slot partials BF16 (in R_z bytes 4MB..8MB) ----
__global__ __launch_bounds__(512, 2) void pv_kernel(
    const u16* __restrict__ P, const u16* __restrict__ VTb,
    float* __restrict__ out, char* __restrict__ R) {
  __shared__ __align__(16) u16 lds[81920];
  const int cls = blockIdx.x, n = blockIdx.y;
  const size_t z = blockIdx.z;
  const int m = CPM[cls], k0 = CPK[cls], ntc = CPN[cls], sl = CPS[cls];
  const u16* Ap = P + z * 2048 * 2048 + (size_t)m * 256 * 2048 + (size_t)k0 * 64;
  const u16* Bp = VTb + z * 1024 * 2048 + (size_t)n * 256 * 2048 + (size_t)k0 * 64;
  if (sl == 0) {
    gemm_core3<float>(lds, Ap, Bp, out + z * 2048 * 1024, ntc,
                      2048, 2048, 1024, m * 256, n * 256);
  } else if (sl == 1) {
    u16* s1 = (u16*)(R + z * (8ul << 20) + (4ul << 20)) - (size_t)512 * 1024;
    gemm_core3<u16>(lds, Ap, Bp, s1, ntc, 2048, 2048, 1024, m * 256, n * 256);
  } else {
    u16* s2 = (u16*)(R + z * (8ul << 20) + (7ul << 20)) - (size_t)1536 * 1024;
    gemm_core3<u16>(lds, Ap, Bp, s2, ntc, 2048, 2048, 1024, m * 256, n * 256);
  }
}

// ---- out += slot1 (+slot2 for m>=6); bf16 slots, fixed order ----
__global__ __launch_bounds__(256) void reduce_kernel(float* __restrict__ out,
                                                     const char* __restrict__ R) {
  const int j = blockIdx.x;
  const int m = 2 + (j >> 5), z = (j >> 3) & 3, s = j & 7;
  float* ob = out + (size_t)z * 2048 * 1024;
  const u16* s1 = (const u16*)(R + (size_t)z * (8ul << 20) + (4ul << 20));
  const u16* s2 = (const u16*)(R + (size_t)z * (8ul << 20) + (7ul << 20));
  const int r0 = m * 256 + s * 32;
  for (int k = threadIdx.x; k < 32 * 256; k += 256) {
    const int rr = r0 + (k >> 8), cc = k & 255;
    float4 o = ((float4*)(ob + (size_t)rr * 1024))[cc];
    ushort4 a = ((const ushort4*)(s1 + (size_t)(rr - 512) * 1024))[cc];
    o.x += bf2f(a.x); o.y += bf2f(a.y); o.z += bf2f(a.z); o.w += bf2f(a.w);
    if (m >= 6) {
      ushort4 b = ((const ushort4*)(s2 + (size_t)(rr - 1536) * 1024))[cc];
      o.x += bf2f(b.x); o.y += bf2f(b.y); o.z += bf2f(b.z); o.w += bf2f(b.w);
    }
    ((float4*)(ob + (size_t)rr * 1024))[cc] = o;
  }
}

extern "C" void kernel_launch(void* const* d_in, const int* in_sizes, int n_in,
                              void* d_out, int out_size, void* d_ws, size_t ws_size,
                              hipStream_t stream) {
  const float* x  = (const float*)d_in[0];
  const float* Wq = (const float*)d_in[1];
  const float* Wk = (const float*)d_in[2];
  const float* Wv = (const float*)d_in[3];
  float* out = (float*)d_out;

  char* ws = (char*)d_ws;
  u16* xb   = (u16*)(ws);                        // 16 MB  x bf16 [8192][1024]
  u16* wqb  = (u16*)(ws + (16ul << 20));         //  2 MB
  u16* wkb  = (u16*)(ws + (18ul << 20));         //  2 MB
  u16* wvb  = (u16*)(ws + (20ul << 20));         //  2 MB
  u16* Qb   = (u16*)(ws + (22ul << 20));         // 16 MB  Q bf16 [4][2048][1024]
  u16* Kb   = (u16*)(ws + (38ul << 20));         // 16 MB  K bf16
  u16* VTb  = (u16*)(ws + (54ul << 20));         // 16 MB  V^T bf16 [4][1024][2048]
  u16* Sb16 = (u16*)(ws + (70ul << 20));         // 32 MB  S/P bf16 [4][2048][2048]
  char* R   = ws + (102ul << 20);                // 32 MB  per z (8MB): vtK partials
                                                 //        f32 (0..4MB, dead after
                                                 //        vtfix) | slot1 u16 (4..7MB)
                                                 //        | slot2 u16 (7..8MB)

  cvt_all_kernel<<<11264, 256, 0, stream>>>(x, Wq, Wk, Wv, xb, wqb, wkb, wvb);

  proj_qk_kernel<<<256, 512, 0, stream>>>(xb, wqb, wkb, Qb, Kb);

  qktvt_kernel<<<256, 512, 0, stream>>>(Qb, Kb, Sb16, wvb, xb, VTb);

  smvt_kernel<<<576, 512, 0, stream>>>(Sb16, (float*)R, wvb, xb);

  vtfix_kernel<<<32, 256, 0, stream>>>((const float*)R, VTb);

  pv_kernel<<<dim3(16, 4, 4), 512, 0, stream>>>(Sb16, VTb, out, R);

  reduce_kernel<<<192, 256, 0, stream>>>(out, R);
}

// Round 15
// 158.478 us; speedup vs baseline: 1.0946x; 1.0946x over previous
//
#include <hip/hip_runtime.h>

typedef unsigned short u16;
typedef unsigned int u32;
typedef __bf16 bf16x8 __attribute__((ext_vector_type(8)));
typedef float f32x4 __attribute__((ext_vector_type(4)));

#define AS1 __attribute__((address_space(1)))
#define AS3 __attribute__((address_space(3)))

// ---- fp32 <-> bf16 ----
__device__ inline u16 f2bf(float f) {
  union { float f; unsigned u; } a; a.f = f;
  unsigned u = a.u;
  return (u16)((u + 0x7fffu + ((u >> 16) & 1u)) >> 16);
}
__device__ inline float bf2f(u16 h) {
  union { unsigned u; float f; } a; a.u = ((u32)h) << 16; return a.f;
}

// ---- all fp32 -> bf16 converts in one dispatch ----
__global__ __launch_bounds__(256) void cvt_all_kernel(
    const float* __restrict__ x, const float* __restrict__ wq,
    const float* __restrict__ wk, const float* __restrict__ wv,
    u16* __restrict__ xb, u16* __restrict__ wqb,
    u16* __restrict__ wkb, u16* __restrict__ wvb) {
  int bid = blockIdx.x;
  const float* in; u16* out;
  if (bid < 8192) { in = x; out = xb; }
  else if (bid < 9216) { in = wq; out = wqb; bid -= 8192; }
  else if (bid < 10240) { in = wk; out = wkb; bid -= 9216; }
  else { in = wv; out = wvb; bid -= 10240; }
  size_t i = ((size_t)bid * 256 + threadIdx.x) * 4;
  float4 v = *(const float4*)(in + i);
  ushort4 o;
  o.x = f2bf(v.x); o.y = f2bf(v.y); o.z = f2bf(v.z); o.w = f2bf(v.w);
  *(ushort4*)(out + i) = o;
}

// ============================================================================
// 256x256 8-wave GEMM core, depth-2 prefetch, 160KB LDS, 1 block/CU.
// (r12 core3 — proven; used for proj and pv where operand residency/classes fit)
// ============================================================================
template <typename CT>
__device__ __forceinline__ void gemm_core3(
    u16* __restrict__ lds,
    const u16* __restrict__ A, const u16* __restrict__ B, CT* __restrict__ C,
    int nt, int lda, int ldb, int ldc, int m0, int n0) {
  const int tid = threadIdx.x;
  const int ln = tid & 63, wv = tid >> 6;
  const int wr = wv >> 2, wc = wv & 3;

  auto sweep = [&](const u16* src, int ld, int t, int s, int base) {
    const int c = s * 512 + tid;
    const int row = c >> 3, slot = c & 7;
    const int col = (slot ^ (row & 7)) * 8;
    __builtin_amdgcn_global_load_lds(
        (const AS1 void*)(src + (size_t)row * ld + (size_t)t * 64 + col),
        (AS3 void*)(&lds[base + c * 8]), 16, 0, 0);
  };

  f32x4 acc[8][4] = {};

#pragma unroll
  for (int s = 0; s < 4; ++s) sweep(B, ldb, 0, s, 49152);
#pragma unroll
  for (int s = 0; s < 4; ++s) sweep(A, lda, 0, s, 0);
  if (nt > 1) {
#pragma unroll
    for (int s = 0; s < 4; ++s) sweep(B, ldb, 1, s, 65536);
#pragma unroll
    for (int s = 0; s < 4; ++s) sweep(A, lda, 1, s, 16384);
    asm volatile("s_waitcnt vmcnt(8)" ::: "memory");
  } else {
    asm volatile("s_waitcnt vmcnt(0)" ::: "memory");
  }
  __builtin_amdgcn_s_barrier();

  for (int t = 0; t < nt; ++t) {
    const u16* La = &lds[(t % 3) * 16384];
    const u16* Lb = &lds[49152 + (t & 1) * 16384];
    const int an = ((t + 2) % 3) * 16384;
    const int bn = 49152 + (t & 1) * 16384;
    bf16x8 bfr[4][2];
#pragma unroll
    for (int q = 0; q < 4; ++q) {
      if (q == 0) {
        __builtin_amdgcn_sched_barrier(0);
#pragma unroll
        for (int ni = 0; ni < 4; ++ni)
#pragma unroll
          for (int ks = 0; ks < 2; ++ks) {
            const int row = wc * 64 + ni * 16 + (ln & 15);
            const int kc = ks * 4 + (ln >> 4);
            bfr[ni][ks] = *(const bf16x8*)&Lb[row * 64 + ((kc ^ (row & 7)) << 3)];
          }
      }
      bf16x8 afr[2][2];
#pragma unroll
      for (int mi = 0; mi < 2; ++mi)
#pragma unroll
        for (int ks = 0; ks < 2; ++ks) {
          const int row = wr * 128 + (q * 2 + mi) * 16 + (ln & 15);
          const int kc = ks * 4 + (ln >> 4);
          afr[mi][ks] = *(const bf16x8*)&La[row * 64 + ((kc ^ (row & 7)) << 3)];
        }
      if (t + 2 < nt) {
        if (q == 0)      { sweep(A, lda, t + 2, 0, an); sweep(A, lda, t + 2, 1, an); }
        else if (q == 1) { sweep(A, lda, t + 2, 2, an); sweep(A, lda, t + 2, 3, an); }
        else if (q == 2) { sweep(B, ldb, t + 2, 0, bn); sweep(B, ldb, t + 2, 1, bn); }
        else             { sweep(B, ldb, t + 2, 2, bn); sweep(B, ldb, t + 2, 3, bn); }
      }

      __builtin_amdgcn_s_barrier();
      __builtin_amdgcn_s_setprio(1);
#pragma unroll
      for (int mi = 0; mi < 2; ++mi)
#pragma unroll
        for (int ni = 0; ni < 4; ++ni)
#pragma unroll
          for (int ks = 0; ks < 2; ++ks)
            acc[q * 2 + mi][ni] = __builtin_amdgcn_mfma_f32_16x16x32_bf16(
                afr[mi][ks], bfr[ni][ks], acc[q * 2 + mi][ni], 0, 0, 0);
      __builtin_amdgcn_s_setprio(0);
      if (q == 3) {
        if (t + 2 < nt)      asm volatile("s_waitcnt vmcnt(8)" ::: "memory");
        else if (t + 1 < nt) asm volatile("s_waitcnt vmcnt(0)" ::: "memory");
      }
      __builtin_amdgcn_s_barrier();
    }
  }

#pragma unroll
  for (int mi = 0; mi < 8; ++mi) {
    const int rbase = m0 + wr * 128 + mi * 16 + (ln >> 4) * 4;
#pragma unroll
    for (int ni = 0; ni < 4; ++ni) {
      const int col = n0 + wc * 64 + ni * 16 + (ln & 15);
#pragma unroll
      for (int r = 0; r < 4; ++r) {
        const float v = acc[mi][ni][r];
        CT* ptr = &C[(size_t)(rbase + r) * ldc + col];
        if constexpr (sizeof(CT) == 4) *(float*)ptr = v;
        else                           *ptr = f2bf(v);
      }
    }
  }
}

// ============================================================================
// 128x128 8-wave GEMM core, depth-2 prefetch, 80KB LDS -> 2 BLOCKS/CU (TLP).
//   Wave-tile 32x64 (4M x 2N wave grid). BK=64 keeps the conflict-free 8-slot
//   XOR swizzle. A ring-3 @ 0/8192/16384 (u16), B ping-pong @ 24576/32768.
//   2 phases/tile: ph0 {reads, stage A(t+2), bar, 8 MFMA, bar};
//                  ph1 {stage B(t+2)->B[t&1] (dead after ph0 reads), bar,
//                       8 MFMA, vmcnt(4), bar}.
//   FIFO: 4 loads/thread/tile; at ph1 wait: 8 outstanding, oldest 4 = t+1. ✓
// ============================================================================
template <typename CT>
__device__ __forceinline__ void gemm_core128(
    u16* __restrict__ lds,
    const u16* __restrict__ A, const u16* __restrict__ B, CT* __restrict__ C,
    int nt, int lda, int ldb, int ldc, int m0, int n0) {
  const int tid = threadIdx.x;
  const int ln = tid & 63, wv = tid >> 6;
  const int wr = wv >> 1, wc = wv & 1;   // 4 x 2 wave grid

  auto sweep = [&](const u16* src, int ld, int t, int s, int base) {
    const int c = s * 512 + tid;         // 0..1023 chunks of 16B; 8/row (128B)
    const int row = c >> 3, slot = c & 7;
    const int col = (slot ^ (row & 7)) * 8;
    __builtin_amdgcn_global_load_lds(
        (const AS1 void*)(src + (size_t)row * ld + (size_t)t * 64 + col),
        (AS3 void*)(&lds[base + c * 8]), 16, 0, 0);
  };

  f32x4 acc[2][4] = {};

  // prologue: B(0),A(0),B(1),A(1) = 8 loads; vmcnt(4) completes tile-0 pair
  sweep(B, ldb, 0, 0, 24576); sweep(B, ldb, 0, 1, 24576);
  sweep(A, lda, 0, 0, 0);     sweep(A, lda, 0, 1, 0);
  if (nt > 1) {
    sweep(B, ldb, 1, 0, 32768); sweep(B, ldb, 1, 1, 32768);
    sweep(A, lda, 1, 0, 8192);  sweep(A, lda, 1, 1, 8192);
    asm volatile("s_waitcnt vmcnt(4)" ::: "memory");
  } else {
    asm volatile("s_waitcnt vmcnt(0)" ::: "memory");
  }
  __builtin_amdgcn_s_barrier();

  for (int t = 0; t < nt; ++t) {
    const u16* La = &lds[(t % 3) * 8192];
    const u16* Lb = &lds[24576 + (t & 1) * 8192];
    const int an = ((t + 2) % 3) * 8192;        // holds A(t-1): dead
    const int bn = 24576 + (t & 1) * 8192;      // self: dead after ph0 reads

    // ---- ph0: all fragment reads + A(t+2) staging + first MFMA half ----
    __builtin_amdgcn_sched_barrier(0);          // pin reads below prev barrier
    bf16x8 bfr[4][2], afr[2][2];
#pragma unroll
    for (int ni = 0; ni < 4; ++ni)
#pragma unroll
      for (int ks = 0; ks < 2; ++ks) {
        const int row = wc * 64 + ni * 16 + (ln & 15);
        const int kc = ks * 4 + (ln >> 4);
        bfr[ni][ks] = *(const bf16x8*)&Lb[row * 64 + ((kc ^ (row & 7)) << 3)];
      }
#pragma unroll
    for (int mi = 0; mi < 2; ++mi)
#pragma unroll
      for (int ks = 0; ks < 2; ++ks) {
        const int row = wr * 32 + mi * 16 + (ln & 15);
        const int kc = ks * 4 + (ln >> 4);
        afr[mi][ks] = *(const bf16x8*)&La[row * 64 + ((kc ^ (row & 7)) << 3)];
      }
    if (t + 2 < nt) { sweep(A, lda, t + 2, 0, an); sweep(A, lda, t + 2, 1, an); }
    __builtin_amdgcn_s_barrier();
    __builtin_amdgcn_s_setprio(1);
#pragma unroll
    for (int ni = 0; ni < 4; ++ni)
#pragma unroll
      for (int ks = 0; ks < 2; ++ks)
        acc[0][ni] = __builtin_amdgcn_mfma_f32_16x16x32_bf16(
            afr[0][ks], bfr[ni][ks], acc[0][ni], 0, 0, 0);
    __builtin_amdgcn_s_setprio(0);
    __builtin_amdgcn_s_barrier();

    // ---- ph1: B(t+2) staging + second MFMA half + counted wait ----
    if (t + 2 < nt) { sweep(B, ldb, t + 2, 0, bn); sweep(B, ldb, t + 2, 1, bn); }
    __builtin_amdgcn_s_barrier();
    __builtin_amdgcn_s_setprio(1);
#pragma unroll
    for (int ni = 0; ni < 4; ++ni)
#pragma unroll
      for (int ks = 0; ks < 2; ++ks)
        acc[1][ni] = __builtin_amdgcn_mfma_f32_16x16x32_bf16(
            afr[1][ks], bfr[ni][ks], acc[1][ni], 0, 0, 0);
    __builtin_amdgcn_s_setprio(0);
    if (t + 2 < nt)      asm volatile("s_waitcnt vmcnt(4)" ::: "memory");
    else if (t + 1 < nt) asm volatile("s_waitcnt vmcnt(0)" ::: "memory");
    __builtin_amdgcn_s_barrier();
  }

  // epilogue: D col = lane&15 (n), row = (lane>>4)*4 + reg (m)
#pragma unroll
  for (int mi = 0; mi < 2; ++mi) {
    const int rbase = m0 + wr * 32 + mi * 16 + (ln >> 4) * 4;
#pragma unroll
    for (int ni = 0; ni < 4; ++ni) {
      const int col = n0 + wc * 64 + ni * 16 + (ln & 15);
#pragma unroll
      for (int r = 0; r < 4; ++r) {
        const float v = acc[mi][ni][r];
        CT* ptr = &C[(size_t)(rbase + r) * ldc + col];
        if constexpr (sizeof(CT) == 4) *(float*)ptr = v;
        else                           *ptr = f2bf(v);
      }
    }
  }
}

// ---- Q = x Wq^T, K = x Wk^T: 256 blocks of 256x256 (exactly 1 round) ----
__global__ __launch_bounds__(512, 2) void proj_qk_kernel(
    const u16* __restrict__ xb, const u16* __restrict__ wqb,
    const u16* __restrict__ wkb, u16* __restrict__ Qb, u16* __restrict__ Kb) {
  __shared__ __align__(16) u16 lds[81920];
  const int bid = blockIdx.x;
  const int w = bid >> 7, r = bid & 127;
  const int rb = r >> 2, n0 = (r & 3) * 256;
  const u16* B = w ? wkb : wqb;
  u16* C = w ? Kb : Qb;
  gemm_core3<u16>(lds, xb + (size_t)rb * 256 * 1024, B + (size_t)n0 * 1024,
                  C, 16, 1024, 1024, 1024, rb * 256, n0);
}

// ---- qktvt128: 1056 blocks of 128x128, 80KB LDS -> 2/CU.
//   items 0..543:  qkt lower-tri 128-tiles (136 per z), S bf16.
//   items 544..1055: vt 128-tiles (full K=1024 in-block: NO partials/vtfix).
//   Bijective XCD swizzle (1056 % 8 == 0). ----
__global__ __launch_bounds__(512, 4) void qktvt128_kernel(
    const u16* __restrict__ Qb, const u16* __restrict__ Kb, u16* __restrict__ Sb16,
    const u16* __restrict__ wvb, const u16* __restrict__ xb, u16* __restrict__ VTb) {
  __shared__ __align__(16) u16 lds[40960];
  const int bid = blockIdx.x;
  const int item = (bid & 7) * 132 + (bid >> 3);   // bijective 0..1055
  if (item < 544) {
    const int z = item / 136, ti = item % 136;
    int i = 0;
    while ((i + 1) * (i + 2) / 2 <= ti) ++i;
    const int j = ti - i * (i + 1) / 2;            // j <= i
    gemm_core128<u16>(lds,
        Qb + ((size_t)z * 2048 + i * 128) * 1024,
        Kb + ((size_t)z * 2048 + j * 128) * 1024,
        Sb16 + (size_t)z * 2048 * 2048,
        16, 1024, 1024, 2048, i * 128, j * 128);
  } else {
    const int v = item - 544;                      // 0..511
    const int z = v >> 7, r = v & 127;
    const int d = r >> 4, k = r & 15;
    gemm_core128<u16>(lds, wvb + (size_t)d * 128 * 1024,
                      xb + ((size_t)z * 2048 + k * 128) * 1024,
                      VTb + (size_t)z * 1024 * 2048,
                      16, 1024, 1024, 2048, d * 128, k * 128);
  }
}

// ---- softmax on bf16 S: 512 blocks, 16 rows each, desc-m; P bf16 in place.
//   Rows read garbage in never-written upper tiles -> masked to -inf -> P=0. ----
__global__ __launch_bounds__(512) void sm_kernel(u16* __restrict__ Sb16) {
  const int j = blockIdx.x;
  const int m = 7 - (j >> 6), z = (j >> 4) & 3, s = j & 15;
  const int iters = (m + 2) >> 1;            // ceil((m+1)*256 / 512)
  const int tid = threadIdx.x;
  const int wvid = tid >> 6, lane = tid & 63;
  u16* S0 = Sb16 + (size_t)z * 2048 * 2048;
  for (int rr = wvid; rr < 16; rr += 8) {
    const int r = m * 256 + s * 16 + rr;
    u16* row = S0 + (size_t)r * 2048;
    float vals[4][8];
    float mx = -3.4e38f;
#pragma unroll
    for (int it2 = 0; it2 < 4; ++it2)
      if (it2 < iters) {
        const int idx8 = it2 * 512 + lane * 8;
        uint4 w = *(const uint4*)(row + idx8);
        const u32 ws[4] = {w.x, w.y, w.z, w.w};
#pragma unroll
        for (int e = 0; e < 8; ++e) {
          const u16 hb = (u16)(ws[e >> 1] >> ((e & 1) * 16));
          const float xv = bf2f(hb) * 0.03125f;
          vals[it2][e] = (idx8 + e <= r) ? xv : -3.4e38f;
          mx = fmaxf(mx, vals[it2][e]);
        }
      }
#pragma unroll
    for (int o = 32; o; o >>= 1) mx = fmaxf(mx, __shfl_xor(mx, o, 64));
    float sum = 0.f;
#pragma unroll
    for (int it2 = 0; it2 < 4; ++it2)
      if (it2 < iters) {
#pragma unroll
        for (int e = 0; e < 8; ++e) {
          const float pp = __expf(vals[it2][e] - mx);
          vals[it2][e] = pp;
          sum += pp;
        }
      }
#pragma unroll
    for (int o = 32; o; o >>= 1) sum += __shfl_xor(sum, o, 64);
    const float rcp = 1.f / sum;
#pragma unroll
    for (int it2 = 0; it2 < 4; ++it2)
      if (it2 < iters) {
        const int idx8 = it2 * 512 + lane * 8;
        uint4 w;
        u32 wo[4];
#pragma unroll
        for (int e2 = 0; e2 < 4; ++e2) {
          const u16 lo = f2bf(vals[it2][e2 * 2] * rcp);
          const u16 hi = f2bf(vals[it2][e2 * 2 + 1] * rcp);
          wo[e2] = (u32)lo | ((u32)hi << 16);
        }
        w.x = wo[0]; w.y = wo[1]; w.z = wo[2]; w.w = wo[3];
        *(uint4*)(row + idx8) = w;
      }
  }
}

// pv chunk classes (desc nt): m-tile, k0 (K-tiles), nt, slot (0=out,1=slot1,2=slot2)
__constant__ signed char CPM[16] = {5,5,7,7,7,6,4,4,6,6,3,3,1,2,2,0};
__constant__ signed char CPK[16] = {0,12,0,11,22,0,0,10,10,19,0,8,0,0,6,0};
__constant__ signed char CPN[16] = {12,12,11,11,10,10,10,10,9,9,8,8,8,6,6,4};
__constant__ signed char CPS[16] = {0,1,0,1,2,0,0,1,1,2,0,1,0,0,1,0};

// ---- O_b = P_b VT_b^T; slot partials BF16 (in R_z bytes 4MB..8MB) ----
__global__ __launch_bounds__(512, 2) void pv_kernel(
    const u16* __restrict__ P, const u16* __restrict__ VTb,
    float* __restrict__ out, char* __restrict__ R) {
  __shared__ __align__(16) u16 lds[81920];
  const int cls = blockIdx.x, n = blockIdx.y;
  const size_t z = blockIdx.z;
  const int m = CPM[cls], k0 = CPK[cls], ntc = CPN[cls], sl = CPS[cls];
  const u16* Ap = P + z * 2048 * 2048 + (size_t)m * 256 * 2048 + (size_t)k0 * 64;
  const u16* Bp = VTb + z * 1024 * 2048 + (size_t)n * 256 * 2048 + (size_t)k0 * 64;
  if (sl == 0) {
    gemm_core3<float>(lds, Ap, Bp, out + z * 2048 * 1024, ntc,
                      2048, 2048, 1024, m * 256, n * 256);
  } else if (sl == 1) {
    u16* s1 = (u16*)(R + z * (8ul << 20) + (4ul << 20)) - (size_t)512 * 1024;
    gemm_core3<u16>(lds, Ap, Bp, s1, ntc, 2048, 2048, 1024, m * 256, n * 256);
  } else {
    u16* s2 = (u16*)(R + z * (8ul << 20) + (7ul << 20)) - (size_t)1536 * 1024;
    gemm_core3<u16>(lds, Ap, Bp, s2, ntc, 2048, 2048, 1024, m * 256, n * 256);
  }
}

// ---- out += slot1 (+slot2 for m>=6); bf16 slots, fixed order ----
__global__ __launch_bounds__(256) void reduce_kernel(float* __restrict__ out,
                                                     const char* __restrict__ R) {
  const int j = blockIdx.x;
  const int m = 2 + (j >> 5), z = (j >> 3) & 3, s = j & 7;
  float* ob = out + (size_t)z * 2048 * 1024;
  const u16* s1 = (const u16*)(R + (size_t)z * (8ul << 20) + (4ul << 20));
  const u16* s2 = (const u16*)(R + (size_t)z * (8ul << 20) + (7ul << 20));
  const int r0 = m * 256 + s * 32;
  for (int k = threadIdx.x; k < 32 * 256; k += 256) {
    const int rr = r0 + (k >> 8), cc = k & 255;
    float4 o = ((float4*)(ob + (size_t)rr * 1024))[cc];
    ushort4 a = ((const ushort4*)(s1 + (size_t)(rr - 512) * 1024))[cc];
    o.x += bf2f(a.x); o.y += bf2f(a.y); o.z += bf2f(a.z); o.w += bf2f(a.w);
    if (m >= 6) {
      ushort4 b = ((const ushort4*)(s2 + (size_t)(rr - 1536) * 1024))[cc];
      o.x += bf2f(b.x); o.y += bf2f(b.y); o.z += bf2f(b.z); o.w += bf2f(b.w);
    }
    ((float4*)(ob + (size_t)rr * 1024))[cc] = o;
  }
}

extern "C" void kernel_launch(void* const* d_in, const int* in_sizes, int n_in,
                              void* d_out, int out_size, void* d_ws, size_t ws_size,
                              hipStream_t stream) {
  const float* x  = (const float*)d_in[0];
  const float* Wq = (const float*)d_in[1];
  const float* Wk = (const float*)d_in[2];
  const float* Wv = (const float*)d_in[3];
  float* out = (float*)d_out;

  char* ws = (char*)d_ws;
  u16* xb   = (u16*)(ws);                        // 16 MB  x bf16 [8192][1024]
  u16* wqb  = (u16*)(ws + (16ul << 20));         //  2 MB
  u16* wkb  = (u16*)(ws + (18ul << 20));         //  2 MB
  u16* wvb  = (u16*)(ws + (20ul << 20));         //  2 MB
  u16* Qb   = (u16*)(ws + (22ul << 20));         // 16 MB  Q bf16 [4][2048][1024]
  u16* Kb   = (u16*)(ws + (38ul << 20));         // 16 MB  K bf16
  u16* VTb  = (u16*)(ws + (54ul << 20));         // 16 MB  V^T bf16 [4][1024][2048]
  u16* Sb16 = (u16*)(ws + (70ul << 20));         // 32 MB  S/P bf16 [4][2048][2048]
  char* R   = ws + (102ul << 20);                // 32 MB  per z (8MB): slot1 u16
                                                 //        (4..7MB) | slot2 u16 (7..8MB)

  cvt_all_kernel<<<11264, 256, 0, stream>>>(x, Wq, Wk, Wv, xb, wqb, wkb, wvb);

  proj_qk_kernel<<<256, 512, 0, stream>>>(xb, wqb, wkb, Qb, Kb);

  qktvt128_kernel<<<1056, 512, 0, stream>>>(Qb, Kb, Sb16, wvb, xb, VTb);

  sm_kernel<<<512, 512, 0, stream>>>(Sb16);

  pv_kernel<<<dim3(16, 4, 4), 512, 0, stream>>>(Sb16, VTb, out, R);

  reduce_kernel<<<192, 256, 0, stream>>>(out, R);
}